// Round 1
// baseline (2210.156 us; speedup 1.0000x reference)
//
#include <hip/hip_runtime.h>

#define BATCH 32
#define NROWS 1024
#define MCOLS 1024
#define INV_EPS 10.0f
#define N_ITERS 20

// v = 0
__global__ __launch_bounds__(256) void init_v(float* __restrict__ v) {
    v[blockIdx.x * 256 + threadIdx.x] = 0.f;
}

// u[b][n] = -log( sum_m exp(-10*D[b][n][m] + v[b][m]) )
// grid: BATCH*NROWS/4 blocks of 256 (4 waves, one row per wave)
__global__ __launch_bounds__(256) void row_pass(const float* __restrict__ D,
                                                const float* __restrict__ v,
                                                float* __restrict__ u) {
    __shared__ float vs[MCOLS];
    int row0 = blockIdx.x << 2;
    int b = row0 >> 10;
    const float* vb = v + (b << 10);
    for (int i = threadIdx.x; i < MCOLS; i += 256) vs[i] = vb[i];
    __syncthreads();
    int wave = threadIdx.x >> 6, lane = threadIdx.x & 63;
    int row = row0 + wave;
    const float4* Dr = (const float4*)(D + ((size_t)row << 10));
    float s = 0.f;
#pragma unroll
    for (int k = 0; k < 4; ++k) {
        int idx = lane + (k << 6);
        float4 d = Dr[idx];
        int m = idx << 2;
        s += __expf(fmaf(d.x, -INV_EPS, vs[m + 0]));
        s += __expf(fmaf(d.y, -INV_EPS, vs[m + 1]));
        s += __expf(fmaf(d.z, -INV_EPS, vs[m + 2]));
        s += __expf(fmaf(d.w, -INV_EPS, vs[m + 3]));
    }
#pragma unroll
    for (int off = 32; off; off >>= 1) s += __shfl_down(s, off, 64);
    if (lane == 0) u[row] = -__logf(s);
}

// v[b][m] = -log( sum_n exp(-10*D[b][n][m] + u[b][n]) )
// grid: BATCH * (MCOLS/64) = 512 blocks of 256; lane -> column, 4 waves split n
__global__ __launch_bounds__(256) void col_pass(const float* __restrict__ D,
                                                const float* __restrict__ u,
                                                float* __restrict__ v) {
    int b = blockIdx.x >> 4;
    int m0 = (blockIdx.x & 15) << 6;
    int wave = threadIdx.x >> 6, lane = threadIdx.x & 63;
    const float* Db = D + ((size_t)b << 20);
    const float* ub = u + (b << 10);
    float s = 0.f;
    for (int n = wave; n < NROWS; n += 4) {
        float un = ub[n];  // wave-uniform broadcast load
        float d = Db[((size_t)n << 10) + m0 + lane];
        s += __expf(fmaf(d, -INV_EPS, un));
    }
    __shared__ float sm[4][64];
    sm[wave][lane] = s;
    __syncthreads();
    if (threadIdx.x < 64) {
        float t = sm[0][lane] + sm[1][lane] + sm[2][lane] + sm[3][lane];
        v[(b << 10) + m0 + lane] = -__logf(t);
    }
}

// partials[blk] = sum over 4 rows of sum_m exp(K0 + u + v) * D
__global__ __launch_bounds__(256) void loss_pass(const float* __restrict__ D,
                                                 const float* __restrict__ u,
                                                 const float* __restrict__ v,
                                                 float* __restrict__ partials) {
    __shared__ float vs[MCOLS];
    int row0 = blockIdx.x << 2;
    int b = row0 >> 10;
    const float* vb = v + (b << 10);
    for (int i = threadIdx.x; i < MCOLS; i += 256) vs[i] = vb[i];
    __syncthreads();
    int wave = threadIdx.x >> 6, lane = threadIdx.x & 63;
    int row = row0 + wave;
    float ur = u[row];
    const float4* Dr = (const float4*)(D + ((size_t)row << 10));
    float s = 0.f;
#pragma unroll
    for (int k = 0; k < 4; ++k) {
        int idx = lane + (k << 6);
        float4 d = Dr[idx];
        int m = idx << 2;
        s += __expf(fmaf(d.x, -INV_EPS, ur + vs[m + 0])) * d.x;
        s += __expf(fmaf(d.y, -INV_EPS, ur + vs[m + 1])) * d.y;
        s += __expf(fmaf(d.z, -INV_EPS, ur + vs[m + 2])) * d.z;
        s += __expf(fmaf(d.w, -INV_EPS, ur + vs[m + 3])) * d.w;
    }
#pragma unroll
    for (int off = 32; off; off >>= 1) s += __shfl_down(s, off, 64);
    __shared__ float ws4[4];
    if (lane == 0) ws4[wave] = s;
    __syncthreads();
    if (threadIdx.x == 0) partials[blockIdx.x] = ws4[0] + ws4[1] + ws4[2] + ws4[3];
}

__global__ __launch_bounds__(1024) void final_reduce(const float* __restrict__ partials,
                                                     float* __restrict__ out) {
    float s = 0.f;
    for (int i = threadIdx.x; i < (BATCH * NROWS / 4); i += 1024) s += partials[i];
#pragma unroll
    for (int off = 32; off; off >>= 1) s += __shfl_down(s, off, 64);
    __shared__ float sm[16];
    int wave = threadIdx.x >> 6, lane = threadIdx.x & 63;
    if (lane == 0) sm[wave] = s;
    __syncthreads();
    if (threadIdx.x == 0) {
        float t = 0.f;
        for (int i = 0; i < 16; ++i) t += sm[i];
        out[0] = t / (float)BATCH;
    }
}

extern "C" void kernel_launch(void* const* d_in, const int* in_sizes, int n_in,
                              void* d_out, int out_size, void* d_ws, size_t ws_size,
                              hipStream_t stream) {
    const float* D = (const float*)d_in[0];
    float* out = (float*)d_out;
    float* u = (float*)d_ws;                 // BATCH*NROWS floats
    float* v = u + BATCH * NROWS;            // BATCH*MCOLS floats
    float* partials = v + BATCH * MCOLS;     // BATCH*NROWS/4 floats

    init_v<<<(BATCH * MCOLS) / 256, 256, 0, stream>>>(v);
    for (int t = 0; t < N_ITERS; ++t) {
        row_pass<<<BATCH * NROWS / 4, 256, 0, stream>>>(D, v, u);
        col_pass<<<BATCH * (MCOLS / 64), 256, 0, stream>>>(D, u, v);
    }
    loss_pass<<<BATCH * NROWS / 4, 256, 0, stream>>>(D, u, v, partials);
    final_reduce<<<1, 1024, 0, stream>>>(partials, out);
}

// Round 2
// 995.770 us; speedup vs baseline: 2.2195x; 2.2195x over previous
//
#include <hip/hip_runtime.h>

#define BATCH 32
#define NMAT 1024            // rows == cols == 1024
#define NEG_INV_EPS -10.0f
#define N_ITERS 20

__global__ __launch_bounds__(256) void init_v(float* __restrict__ v) {
    v[blockIdx.x * 256 + threadIdx.x] = 0.f;
}

// One fused Sinkhorn iteration (row-major only):
//   u[n]  = -log( sum_m exp(-10*D[n][m]) * exp(v[m]) )
//   P[blk][m] = partial_n( exp(-10*D[n][m]) * (1/S_n) )   where 1/S_n = exp(u[n])
// Block handles rpb consecutive rows (all in one batch); 4 waves, per-wave LDS
// column accumulators (no LDS atomics, no races).
__global__ __launch_bounds__(256) void fused_pass(const float* __restrict__ D,
                                                  const float* __restrict__ v_in,
                                                  float* __restrict__ u_out,
                                                  float* __restrict__ P,
                                                  int rpb) {
    __shared__ float evs[NMAT];
    __shared__ float pc[4][NMAT];
    const int j = blockIdx.x;
    const int row0 = j * rpb;
    const int b = row0 >> 10;
    const int wave = threadIdx.x >> 6, lane = threadIdx.x & 63;

    const float* vb = v_in + (b << 10);
    for (int i = threadIdx.x; i < NMAT; i += 256) evs[i] = __expf(vb[i]);
    for (int i = lane; i < NMAT; i += 64) pc[wave][i] = 0.f;
    __syncthreads();

    const float4* evs4 = (const float4*)evs;
    float4* pcw = (float4*)pc[wave];

    for (int r = row0 + wave; r < row0 + rpb; r += 4) {
        const float4* Dr = (const float4*)(D + ((size_t)r << 10));
        float4 e[4];
        float s = 0.f;
#pragma unroll
        for (int k = 0; k < 4; ++k) {
            float4 d = Dr[lane + (k << 6)];
            float4 ev = evs4[lane + (k << 6)];
            float4 t;
            t.x = __expf(d.x * NEG_INV_EPS);
            t.y = __expf(d.y * NEG_INV_EPS);
            t.z = __expf(d.z * NEG_INV_EPS);
            t.w = __expf(d.w * NEG_INV_EPS);
            e[k] = t;
            s = fmaf(t.x, ev.x, s);
            s = fmaf(t.y, ev.y, s);
            s = fmaf(t.z, ev.z, s);
            s = fmaf(t.w, ev.w, s);
        }
        // butterfly so ALL lanes get the full row sum
#pragma unroll
        for (int off = 1; off < 64; off <<= 1) s += __shfl_xor(s, off, 64);
        if (lane == 0) u_out[r] = -__logf(s);
        float rs = __builtin_amdgcn_rcpf(s);   // exp(u_n) = 1/S
#pragma unroll
        for (int k = 0; k < 4; ++k) {
            float4 a = pcw[lane + (k << 6)];
            a.x = fmaf(e[k].x, rs, a.x);
            a.y = fmaf(e[k].y, rs, a.y);
            a.z = fmaf(e[k].z, rs, a.z);
            a.w = fmaf(e[k].w, rs, a.w);
            pcw[lane + (k << 6)] = a;
        }
    }
    __syncthreads();
    // cross-wave reduce -> per-block partial column sums (coalesced float4)
    const float4 *p0 = (const float4*)pc[0], *p1 = (const float4*)pc[1],
                 *p2 = (const float4*)pc[2], *p3 = (const float4*)pc[3];
    float4* P4 = (float4*)(P + ((size_t)j << 10));
    int i = threadIdx.x;   // exactly 256 float4s per block
    float4 a = p0[i], bb = p1[i], c = p2[i], d = p3[i];
    float4 o;
    o.x = a.x + bb.x + c.x + d.x;
    o.y = a.y + bb.y + c.y + d.y;
    o.z = a.z + bb.z + c.z + d.z;
    o.w = a.w + bb.w + c.w + d.w;
    P4[i] = o;
}

// v[b][m] = -log( sum_j P[b*npb + j][m] );  grid: 32768/256 = 128 blocks
__global__ __launch_bounds__(256) void reduce_v(const float* __restrict__ P,
                                                float* __restrict__ v,
                                                int npb) {
    int g = blockIdx.x * 256 + threadIdx.x;
    int b = g >> 10, m = g & 1023;
    const float* Pb = P + (((size_t)b * npb) << 10) + m;
    float s = 0.f;
    for (int j = 0; j < npb; ++j) s += Pb[(size_t)j << 10];
    v[g] = -__logf(s);
}

// loss partial per block: sum_{rows} exp(u_n) * sum_m exp(-10 d)*exp(v_m)*d
__global__ __launch_bounds__(256) void loss_pass(const float* __restrict__ D,
                                                 const float* __restrict__ u,
                                                 const float* __restrict__ v,
                                                 float* __restrict__ lp,
                                                 int rpb) {
    __shared__ float evs[NMAT];
    const int j = blockIdx.x;
    const int row0 = j * rpb;
    const int b = row0 >> 10;
    const int wave = threadIdx.x >> 6, lane = threadIdx.x & 63;

    const float* vb = v + (b << 10);
    for (int i = threadIdx.x; i < NMAT; i += 256) evs[i] = __expf(vb[i]);
    __syncthreads();

    const float4* evs4 = (const float4*)evs;
    float acc = 0.f;
    for (int r = row0 + wave; r < row0 + rpb; r += 4) {
        const float4* Dr = (const float4*)(D + ((size_t)r << 10));
        float expu = __expf(u[r]);
        float s = 0.f;
#pragma unroll
        for (int k = 0; k < 4; ++k) {
            float4 d = Dr[lane + (k << 6)];
            float4 ev = evs4[lane + (k << 6)];
            s = fmaf(__expf(d.x * NEG_INV_EPS) * d.x, ev.x, s);
            s = fmaf(__expf(d.y * NEG_INV_EPS) * d.y, ev.y, s);
            s = fmaf(__expf(d.z * NEG_INV_EPS) * d.z, ev.z, s);
            s = fmaf(__expf(d.w * NEG_INV_EPS) * d.w, ev.w, s);
        }
        acc = fmaf(expu, s, acc);
    }
#pragma unroll
    for (int off = 1; off < 64; off <<= 1) acc += __shfl_xor(acc, off, 64);
    __shared__ float sm[4];
    if (lane == 0) sm[wave] = acc;
    __syncthreads();
    if (threadIdx.x == 0) lp[j] = sm[0] + sm[1] + sm[2] + sm[3];
}

__global__ __launch_bounds__(256) void final_reduce(const float* __restrict__ lp,
                                                    int n, float* __restrict__ out) {
    float s = 0.f;
    for (int i = threadIdx.x; i < n; i += 256) s += lp[i];
#pragma unroll
    for (int off = 1; off < 64; off <<= 1) s += __shfl_xor(s, off, 64);
    __shared__ float sm[4];
    int wave = threadIdx.x >> 6, lane = threadIdx.x & 63;
    if (lane == 0) sm[wave] = s;
    __syncthreads();
    if (threadIdx.x == 0) out[0] = (sm[0] + sm[1] + sm[2] + sm[3]) / (float)BATCH;
}

extern "C" void kernel_launch(void* const* d_in, const int* in_sizes, int n_in,
                              void* d_out, int out_size, void* d_ws, size_t ws_size,
                              hipStream_t stream) {
    const float* D = (const float*)d_in[0];
    float* out = (float*)d_out;

    // pick blocks-per-batch to fit workspace: u(32K) + v(32K) + P(nb*1024) + lp(nb)
    int npb = 64;
    while (npb > 1) {
        size_t nb = (size_t)BATCH * npb;
        size_t need = ((size_t)65536 + nb * 1024 + nb) * sizeof(float);
        if (need <= ws_size) break;
        npb >>= 1;
    }
    const int nblocks = BATCH * npb;
    const int rpb = NMAT / npb;

    float* u = (float*)d_ws;                     // 32768
    float* v = u + BATCH * NMAT;                 // 32768
    float* P = v + BATCH * NMAT;                 // nblocks*1024
    float* lp = P + (size_t)nblocks * 1024;      // nblocks

    init_v<<<(BATCH * NMAT) / 256, 256, 0, stream>>>(v);
    for (int t = 0; t < N_ITERS; ++t) {
        fused_pass<<<nblocks, 256, 0, stream>>>(D, v, u, P, rpb);
        reduce_v<<<(BATCH * NMAT) / 256, 256, 0, stream>>>(P, v, npb);
    }
    loss_pass<<<nblocks, 256, 0, stream>>>(D, u, v, lp, rpb);
    final_reduce<<<1, 256, 0, stream>>>(lp, nblocks, out);
}

// Round 3
// 708.829 us; speedup vs baseline: 3.1180x; 1.4048x over previous
//
#include <hip/hip_runtime.h>

#define BATCH 32
#define NMAT 1024
#define NPB 64                   // partial-blocks per batch
#define RPB (NMAT / NPB)         // rows per block = 16
#define NBLOCKS (BATCH * NPB)    // 2048
#define NEG_INV_EPS -10.0f
#define N_ITERS 20

__device__ __forceinline__ float4 f4add(float4 a, float4 b) {
    return make_float4(a.x + b.x, a.y + b.y, a.z + b.z, a.w + b.w);
}

// One Sinkhorn iteration, row-major only, register column-accumulators.
//   S_n        = sum_m exp(-10*D[n][m]) * ev[m]          (ev = exp(v), 1 on first pass)
//   P[j][m]   += exp(-10*D[n][m]) / S_n                  (column partials -> next ev)
//   (LAST) Q[j][m] += exp(-10*D[n][m]) * D[n][m] / S_n   (loss column partials)
template <bool FIRST, bool LAST>
__global__ __launch_bounds__(256) void fused_pass(const float* __restrict__ D,
                                                  const float* __restrict__ ev_in,
                                                  float* __restrict__ P,
                                                  float* __restrict__ Q,
                                                  float* __restrict__ out) {
    const int j = blockIdx.x;
    const int row0 = j * RPB;
    const int b = row0 >> 10;
    const int wave = threadIdx.x >> 6, lane = threadIdx.x & 63;

    // Each lane owns 16 fixed columns: float4 indices lane + k*64, k=0..3.
    float4 ev[4];
    if (FIRST) {
        ev[0] = ev[1] = ev[2] = ev[3] = make_float4(1.f, 1.f, 1.f, 1.f);
    } else {
        const float4* evb = (const float4*)(ev_in + (b << 10));
#pragma unroll
        for (int k = 0; k < 4; ++k) ev[k] = evb[lane + (k << 6)];
    }

    float4 acc[4] = {make_float4(0,0,0,0), make_float4(0,0,0,0),
                     make_float4(0,0,0,0), make_float4(0,0,0,0)};
    float4 qacc[4] = {make_float4(0,0,0,0), make_float4(0,0,0,0),
                      make_float4(0,0,0,0), make_float4(0,0,0,0)};

    for (int r = row0 + wave; r < row0 + RPB; r += 4) {
        const float4* Dr = (const float4*)(D + ((size_t)r << 10));
        float4 d[4], t[4];
#pragma unroll
        for (int k = 0; k < 4; ++k) d[k] = Dr[lane + (k << 6)];
        float s = 0.f;
#pragma unroll
        for (int k = 0; k < 4; ++k) {
            t[k].x = __expf(d[k].x * NEG_INV_EPS);
            t[k].y = __expf(d[k].y * NEG_INV_EPS);
            t[k].z = __expf(d[k].z * NEG_INV_EPS);
            t[k].w = __expf(d[k].w * NEG_INV_EPS);
            s = fmaf(t[k].x, ev[k].x, s);
            s = fmaf(t[k].y, ev[k].y, s);
            s = fmaf(t[k].z, ev[k].z, s);
            s = fmaf(t[k].w, ev[k].w, s);
        }
#pragma unroll
        for (int off = 1; off < 64; off <<= 1) s += __shfl_xor(s, off, 64);
        float rs = __builtin_amdgcn_rcpf(s);  // exp(u_n) = 1/S_n
#pragma unroll
        for (int k = 0; k < 4; ++k) {
            acc[k].x = fmaf(t[k].x, rs, acc[k].x);
            acc[k].y = fmaf(t[k].y, rs, acc[k].y);
            acc[k].z = fmaf(t[k].z, rs, acc[k].z);
            acc[k].w = fmaf(t[k].w, rs, acc[k].w);
            if (LAST) {
                qacc[k].x = fmaf(t[k].x * d[k].x, rs, qacc[k].x);
                qacc[k].y = fmaf(t[k].y * d[k].y, rs, qacc[k].y);
                qacc[k].z = fmaf(t[k].z * d[k].z, rs, qacc[k].z);
                qacc[k].w = fmaf(t[k].w * d[k].w, rs, qacc[k].w);
            }
        }
    }

    // cross-wave reduce (one shot through 16 KB LDS), coalesced float4 store
    __shared__ float4 pc[4][256];
#pragma unroll
    for (int k = 0; k < 4; ++k) pc[wave][lane + (k << 6)] = acc[k];
    __syncthreads();
    {
        int i = threadIdx.x;
        float4 o = f4add(f4add(pc[0][i], pc[1][i]), f4add(pc[2][i], pc[3][i]));
        ((float4*)(P + ((size_t)j << 10)))[i] = o;
    }
    if (LAST) {
        __syncthreads();
#pragma unroll
        for (int k = 0; k < 4; ++k) pc[wave][lane + (k << 6)] = qacc[k];
        __syncthreads();
        int i = threadIdx.x;
        float4 o = f4add(f4add(pc[0][i], pc[1][i]), f4add(pc[2][i], pc[3][i]));
        ((float4*)(Q + ((size_t)j << 10)))[i] = o;
        if (j == 0 && threadIdx.x == 0) out[0] = 0.f;  // arm for loss_final atomics
    }
}

// ev[b][m] = 1 / sum_j P[b*NPB + j][m]   (== exp(v), no log/exp round trip)
__global__ __launch_bounds__(256) void reduce_ev(const float* __restrict__ P,
                                                 float* __restrict__ ev) {
    int g = blockIdx.x * 256 + threadIdx.x;  // 32768 threads
    int b = g >> 10, m = g & 1023;
    const float* Pb = P + (((size_t)b * NPB) << 10) + m;
    float s = 0.f;
#pragma unroll 8
    for (int jj = 0; jj < NPB; ++jj) s += Pb[(size_t)jj << 10];
    ev[g] = 1.0f / s;
}

// loss = mean_b sum_m (sum_j Q[j][m]) / (sum_j P[j][m])
__global__ __launch_bounds__(256) void loss_final(const float* __restrict__ P,
                                                  const float* __restrict__ Q,
                                                  float* __restrict__ out) {
    int g = blockIdx.x * 256 + threadIdx.x;
    int b = g >> 10, m = g & 1023;
    const float* Pb = P + (((size_t)b * NPB) << 10) + m;
    const float* Qb = Q + (((size_t)b * NPB) << 10) + m;
    float s = 0.f, q = 0.f;
#pragma unroll 8
    for (int jj = 0; jj < NPB; ++jj) {
        s += Pb[(size_t)jj << 10];
        q += Qb[(size_t)jj << 10];
    }
    float c = q / s;
#pragma unroll
    for (int off = 1; off < 64; off <<= 1) c += __shfl_xor(c, off, 64);
    __shared__ float sm[4];
    int wave = threadIdx.x >> 6, lane = threadIdx.x & 63;
    if (lane == 0) sm[wave] = c;
    __syncthreads();
    if (threadIdx.x == 0)
        atomicAdd(out, (sm[0] + sm[1] + sm[2] + sm[3]) * (1.0f / (float)BATCH));
}

extern "C" void kernel_launch(void* const* d_in, const int* in_sizes, int n_in,
                              void* d_out, int out_size, void* d_ws, size_t ws_size,
                              hipStream_t stream) {
    const float* D = (const float*)d_in[0];
    float* out = (float*)d_out;

    float* ev = (float*)d_ws;                        // 32768 floats
    float* P  = ev + BATCH * NMAT;                   // NBLOCKS*1024 = 8 MB
    float* Q  = P + (size_t)NBLOCKS * NMAT;          // NBLOCKS*1024 = 8 MB

    // pass 1 (ev == 1 implicitly)
    fused_pass<true, false><<<NBLOCKS, 256, 0, stream>>>(D, ev, P, Q, out);
    // passes 2..19
    for (int t = 1; t < N_ITERS - 1; ++t) {
        reduce_ev<<<(BATCH * NMAT) / 256, 256, 0, stream>>>(P, ev);
        fused_pass<false, false><<<NBLOCKS, 256, 0, stream>>>(D, ev, P, Q, out);
    }
    // pass 20: also accumulate loss column partials Q
    reduce_ev<<<(BATCH * NMAT) / 256, 256, 0, stream>>>(P, ev);
    fused_pass<false, true><<<NBLOCKS, 256, 0, stream>>>(D, ev, P, Q, out);
    // loss = mean_b sum_m ΣQ/ΣP
    loss_final<<<(BATCH * NMAT) / 256, 256, 0, stream>>>(P, Q, out);
}

// Round 4
// 558.228 us; speedup vs baseline: 3.9592x; 1.2698x over previous
//
#include <hip/hip_runtime.h>

#define BATCH 32
#define NMAT 1024
#define NPB 64                   // partial-blocks per batch
#define RPB (NMAT / NPB)         // rows per block = 16
#define NBLOCKS (BATCH * NPB)    // 2048
#define N_ITERS 20
#define SHIFT 5.0f               // E stores t' = exp(-10*D + 5); e^5 cancels in P=t/S

typedef _Float16 h8 __attribute__((ext_vector_type(8)));

__device__ __forceinline__ float wave_allsum(float s) {
#pragma unroll
    for (int off = 1; off < 64; off <<= 1) s += __shfl_xor(s, off, 64);
    return s;
}

__device__ __forceinline__ float4 f4add(float4 a, float4 b) {
    return make_float4(a.x + b.x, a.y + b.y, a.z + b.z, a.w + b.w);
}

// Pass 1: read D (fp32), build E = fp16 exp(-10D+5), emit first column partials
// P[j][m] = sum_n t[n][m] / S_n   (ev == 1 on the first iteration).
// Lane owns columns 8c..8c+7 for c = lane + 64*k2, k2 in {0,1}.
__global__ __launch_bounds__(256) void pass1_build(const float* __restrict__ D,
                                                   _Float16* __restrict__ E,
                                                   float* __restrict__ P) {
    const int j = blockIdx.x;
    const int row0 = j * RPB;
    const int wave = threadIdx.x >> 6, lane = threadIdx.x & 63;

    float4 acc[4] = {make_float4(0,0,0,0), make_float4(0,0,0,0),
                     make_float4(0,0,0,0), make_float4(0,0,0,0)};

#pragma unroll
    for (int i = 0; i < RPB / 4; ++i) {
        const int r = row0 + wave + (i << 2);
        const float4* Dr = (const float4*)(D + ((size_t)r << 10));
        h8* Er = (h8*)(E + ((size_t)r << 10));
        float t[16];
        float s = 0.f;
#pragma unroll
        for (int k2 = 0; k2 < 2; ++k2) {
            const int c = lane + (k2 << 6);
            float4 d0 = Dr[2 * c], d1 = Dr[2 * c + 1];
            float* tv = t + (k2 << 3);
            tv[0] = __expf(fmaf(d0.x, -10.f, SHIFT));
            tv[1] = __expf(fmaf(d0.y, -10.f, SHIFT));
            tv[2] = __expf(fmaf(d0.z, -10.f, SHIFT));
            tv[3] = __expf(fmaf(d0.w, -10.f, SHIFT));
            tv[4] = __expf(fmaf(d1.x, -10.f, SHIFT));
            tv[5] = __expf(fmaf(d1.y, -10.f, SHIFT));
            tv[6] = __expf(fmaf(d1.z, -10.f, SHIFT));
            tv[7] = __expf(fmaf(d1.w, -10.f, SHIFT));
            h8 o;
#pragma unroll
            for (int q = 0; q < 8; ++q) o[q] = (_Float16)tv[q];
            Er[c] = o;
#pragma unroll
            for (int q = 0; q < 8; ++q) s += tv[q];
        }
        s = wave_allsum(s);
        const float rs = __builtin_amdgcn_rcpf(s);
#pragma unroll
        for (int k2 = 0; k2 < 2; ++k2) {
            float* tv = t + (k2 << 3);
            float4* a0 = &acc[k2 << 1];
            a0[0].x = fmaf(tv[0], rs, a0[0].x);
            a0[0].y = fmaf(tv[1], rs, a0[0].y);
            a0[0].z = fmaf(tv[2], rs, a0[0].z);
            a0[0].w = fmaf(tv[3], rs, a0[0].w);
            a0[1].x = fmaf(tv[4], rs, a0[1].x);
            a0[1].y = fmaf(tv[5], rs, a0[1].y);
            a0[1].z = fmaf(tv[6], rs, a0[1].z);
            a0[1].w = fmaf(tv[7], rs, a0[1].w);
        }
    }

    __shared__ float4 pc[4][256];
#pragma unroll
    for (int k2 = 0; k2 < 2; ++k2) {
        const int c = lane + (k2 << 6);
        pc[wave][2 * c]     = acc[k2 << 1];
        pc[wave][2 * c + 1] = acc[(k2 << 1) + 1];
    }
    __syncthreads();
    const int i = threadIdx.x;
    float4 o = f4add(f4add(pc[0][i], pc[1][i]), f4add(pc[2][i], pc[3][i]));
    ((float4*)(P + ((size_t)j << 10)))[i] = o;
}

// Iterations 2..20: read E (fp16) + ev, emit column partials P.
// LAST also emits loss partials Q[j][m] = sum_n t*d/S_n with d=(SHIFT-ln t)/10.
template <bool LAST>
__global__ __launch_bounds__(256) void pass_iter(const _Float16* __restrict__ E,
                                                 const float* __restrict__ ev_in,
                                                 float* __restrict__ P,
                                                 float* __restrict__ Q,
                                                 float* __restrict__ out) {
    const int j = blockIdx.x;
    const int row0 = j * RPB;
    const int b = row0 >> 10;
    const int wave = threadIdx.x >> 6, lane = threadIdx.x & 63;

    float ev[16];
    {
        const float4* evb = (const float4*)(ev_in + (b << 10));
#pragma unroll
        for (int k2 = 0; k2 < 2; ++k2) {
            const int c = lane + (k2 << 6);
            float4 e0 = evb[2 * c], e1 = evb[2 * c + 1];
            float* e = ev + (k2 << 3);
            e[0] = e0.x; e[1] = e0.y; e[2] = e0.z; e[3] = e0.w;
            e[4] = e1.x; e[5] = e1.y; e[6] = e1.z; e[7] = e1.w;
        }
    }

    float4 acc[4] = {make_float4(0,0,0,0), make_float4(0,0,0,0),
                     make_float4(0,0,0,0), make_float4(0,0,0,0)};
    float4 qacc[4] = {make_float4(0,0,0,0), make_float4(0,0,0,0),
                      make_float4(0,0,0,0), make_float4(0,0,0,0)};

#pragma unroll
    for (int i = 0; i < RPB / 4; ++i) {
        const int r = row0 + wave + (i << 2);
        const h8* Er = (const h8*)(E + ((size_t)r << 10));
        h8 h0 = Er[lane], h1 = Er[lane + 64];
        float t[16];
#pragma unroll
        for (int q = 0; q < 8; ++q) { t[q] = (float)h0[q]; t[8 + q] = (float)h1[q]; }
        float s = 0.f;
#pragma unroll
        for (int q = 0; q < 16; ++q) s = fmaf(t[q], ev[q], s);
        s = wave_allsum(s);
        const float rs = __builtin_amdgcn_rcpf(s);
#pragma unroll
        for (int k2 = 0; k2 < 2; ++k2) {
            float* tv = t + (k2 << 3);
            float4* a0 = &acc[k2 << 1];
            a0[0].x = fmaf(tv[0], rs, a0[0].x);
            a0[0].y = fmaf(tv[1], rs, a0[0].y);
            a0[0].z = fmaf(tv[2], rs, a0[0].z);
            a0[0].w = fmaf(tv[3], rs, a0[0].w);
            a0[1].x = fmaf(tv[4], rs, a0[1].x);
            a0[1].y = fmaf(tv[5], rs, a0[1].y);
            a0[1].z = fmaf(tv[6], rs, a0[1].z);
            a0[1].w = fmaf(tv[7], rs, a0[1].w);
        }
        if (LAST) {
#pragma unroll
            for (int k2 = 0; k2 < 2; ++k2) {
                float* tv = t + (k2 << 3);
                float4* q0 = &qacc[k2 << 1];
                float w[8];
#pragma unroll
                for (int q = 0; q < 8; ++q) {
                    const float d = (SHIFT - __logf(tv[q])) * 0.1f;
                    w[q] = tv[q] * d;
                }
                q0[0].x = fmaf(w[0], rs, q0[0].x);
                q0[0].y = fmaf(w[1], rs, q0[0].y);
                q0[0].z = fmaf(w[2], rs, q0[0].z);
                q0[0].w = fmaf(w[3], rs, q0[0].w);
                q0[1].x = fmaf(w[4], rs, q0[1].x);
                q0[1].y = fmaf(w[5], rs, q0[1].y);
                q0[1].z = fmaf(w[6], rs, q0[1].z);
                q0[1].w = fmaf(w[7], rs, q0[1].w);
            }
        }
    }

    __shared__ float4 pc[4][256];
#pragma unroll
    for (int k2 = 0; k2 < 2; ++k2) {
        const int c = lane + (k2 << 6);
        pc[wave][2 * c]     = acc[k2 << 1];
        pc[wave][2 * c + 1] = acc[(k2 << 1) + 1];
    }
    __syncthreads();
    {
        const int i = threadIdx.x;
        float4 o = f4add(f4add(pc[0][i], pc[1][i]), f4add(pc[2][i], pc[3][i]));
        ((float4*)(P + ((size_t)j << 10)))[i] = o;
    }
    if (LAST) {
        __syncthreads();
#pragma unroll
        for (int k2 = 0; k2 < 2; ++k2) {
            const int c = lane + (k2 << 6);
            pc[wave][2 * c]     = qacc[k2 << 1];
            pc[wave][2 * c + 1] = qacc[(k2 << 1) + 1];
        }
        __syncthreads();
        const int i = threadIdx.x;
        float4 o = f4add(f4add(pc[0][i], pc[1][i]), f4add(pc[2][i], pc[3][i]));
        ((float4*)(Q + ((size_t)j << 10)))[i] = o;
        if (j == 0 && threadIdx.x == 0) out[0] = 0.f;  // arm loss_final atomics
    }
}

// ev[b][m] = 1 / sum_j P[b*NPB + j][m]
__global__ __launch_bounds__(256) void reduce_ev(const float* __restrict__ P,
                                                 float* __restrict__ ev) {
    int g = blockIdx.x * 256 + threadIdx.x;  // 32768 threads
    int b = g >> 10, m = g & 1023;
    const float* Pb = P + (((size_t)b * NPB) << 10) + m;
    float s = 0.f;
#pragma unroll 8
    for (int jj = 0; jj < NPB; ++jj) s += Pb[(size_t)jj << 10];
    ev[g] = 1.0f / s;
}

// loss = mean_b sum_m (sum_j Q[j][m]) / (sum_j P[j][m])
__global__ __launch_bounds__(256) void loss_final(const float* __restrict__ P,
                                                  const float* __restrict__ Q,
                                                  float* __restrict__ out) {
    int g = blockIdx.x * 256 + threadIdx.x;
    int b = g >> 10, m = g & 1023;
    const float* Pb = P + (((size_t)b * NPB) << 10) + m;
    const float* Qb = Q + (((size_t)b * NPB) << 10) + m;
    float s = 0.f, q = 0.f;
#pragma unroll 8
    for (int jj = 0; jj < NPB; ++jj) {
        s += Pb[(size_t)jj << 10];
        q += Qb[(size_t)jj << 10];
    }
    float c = q / s;
    c = wave_allsum(c);
    __shared__ float sm[4];
    int wave = threadIdx.x >> 6, lane = threadIdx.x & 63;
    if (lane == 0) sm[wave] = c;
    __syncthreads();
    if (threadIdx.x == 0)
        atomicAdd(out, (sm[0] + sm[1] + sm[2] + sm[3]) * (1.0f / (float)BATCH));
}

extern "C" void kernel_launch(void* const* d_in, const int* in_sizes, int n_in,
                              void* d_out, int out_size, void* d_ws, size_t ws_size,
                              hipStream_t stream) {
    const float* D = (const float*)d_in[0];
    float* out = (float*)d_out;

    float* ev = (float*)d_ws;                          // 32768 floats (128 KB)
    float* P  = ev + BATCH * NMAT;                     // 8 MB
    float* Q  = P + (size_t)NBLOCKS * NMAT;            // 8 MB
    _Float16* E = (_Float16*)(Q + (size_t)NBLOCKS * NMAT);  // 64 MB fp16

    // iter 1: build E from D, first column partials (ev == 1)
    pass1_build<<<NBLOCKS, 256, 0, stream>>>(D, E, P);
    // iters 2..19
    for (int t = 1; t < N_ITERS - 1; ++t) {
        reduce_ev<<<(BATCH * NMAT) / 256, 256, 0, stream>>>(P, ev);
        pass_iter<false><<<NBLOCKS, 256, 0, stream>>>(E, ev, P, Q, out);
    }
    // iter 20: also accumulate loss column partials Q
    reduce_ev<<<(BATCH * NMAT) / 256, 256, 0, stream>>>(P, ev);
    pass_iter<true><<<NBLOCKS, 256, 0, stream>>>(E, ev, P, Q, out);
    // loss = mean_b sum_m ΣQ/ΣP
    loss_final<<<(BATCH * NMAT) / 256, 256, 0, stream>>>(P, Q, out);
}